// Round 1
// baseline (374.094 us; speedup 1.0000x reference)
//
#include <hip/hip_runtime.h>
#include <hip/hip_bf16.h>
#include <math.h>

#define BATCH 512

// ---------------- Layer 1: conv 3->16 (3x3 SAME, 64x64) + bn + relu + maxpool2 -> 16x32x32
__global__ __launch_bounds__(256) void k_conv1(const float* __restrict__ x,
    const float* __restrict__ w, const float* __restrict__ cb,
    const float* __restrict__ g, const float* __restrict__ beta,
    const float* __restrict__ m, const float* __restrict__ v,
    float* __restrict__ out)
{
    int t = blockIdx.x * 256 + threadIdx.x;      // 512*1024 threads
    int pw = t & 31, ph = (t >> 5) & 31, b = t >> 10;
    const float* img = x + (size_t)b * 3 * 64 * 64;
    float p[3][4][4];
    int y0 = 2 * ph - 1, xx0 = 2 * pw - 1;
    #pragma unroll
    for (int ic = 0; ic < 3; ++ic)
        #pragma unroll
        for (int dy = 0; dy < 4; ++dy) {
            int y = y0 + dy;
            bool yok = (unsigned)y < 64u;
            #pragma unroll
            for (int dx = 0; dx < 4; ++dx) {
                int xx = xx0 + dx;
                float val = 0.f;
                if (yok && (unsigned)xx < 64u) val = img[(ic * 64 + y) * 64 + xx];
                p[ic][dy][dx] = val;
            }
        }
    float* op = out + (size_t)b * 16 * 1024 + ph * 32 + pw;
    for (int oc = 0; oc < 16; ++oc) {
        float inv = g[oc] * rsqrtf(v[oc] + 1e-5f);
        float bs  = (cb[oc] - m[oc]) * inv + beta[oc];
        float a00 = 0.f, a01 = 0.f, a10 = 0.f, a11 = 0.f;
        #pragma unroll
        for (int ic = 0; ic < 3; ++ic)
            #pragma unroll
            for (int ky = 0; ky < 3; ++ky)
                #pragma unroll
                for (int kx = 0; kx < 3; ++kx) {
                    float wv = w[((oc * 3 + ic) * 3 + ky) * 3 + kx];
                    a00 = fmaf(p[ic][ky][kx],     wv, a00);
                    a01 = fmaf(p[ic][ky][kx + 1], wv, a01);
                    a10 = fmaf(p[ic][ky + 1][kx],     wv, a10);
                    a11 = fmaf(p[ic][ky + 1][kx + 1], wv, a11);
                }
        float r = fmaxf(fmaxf(fmaxf(a00 * inv + bs, 0.f), fmaxf(a01 * inv + bs, 0.f)),
                        fmaxf(fmaxf(a10 * inv + bs, 0.f), fmaxf(a11 * inv + bs, 0.f)));
        op[oc * 1024] = r;
    }
}

// ---------------- Layer 2: conv 16->32 (3x3 SAME, 32x32) + bn + relu + maxpool2 -> 32x16x16
__global__ __launch_bounds__(256) void k_conv2(const float* __restrict__ in,
    const float* __restrict__ w, const float* __restrict__ cb,
    const float* __restrict__ g, const float* __restrict__ beta,
    const float* __restrict__ m, const float* __restrict__ v,
    float* __restrict__ out)
{
    int bid = blockIdx.x;                 // 2048 blocks
    int b = bid >> 2, ocg = bid & 3;      // 8 oc per thread
    int t = threadIdx.x;
    int pw = t & 15, ph = t >> 4;
    const float* src = in + (size_t)b * 16 * 1024;
    float acc[8][4];
    #pragma unroll
    for (int o = 0; o < 8; ++o)
        #pragma unroll
        for (int j = 0; j < 4; ++j) acc[o][j] = 0.f;
    int y0 = 2 * ph - 1, xx0 = 2 * pw - 1;
    for (int ic = 0; ic < 16; ++ic) {
        float p[4][4];
        #pragma unroll
        for (int dy = 0; dy < 4; ++dy) {
            int y = y0 + dy;
            bool yok = (unsigned)y < 32u;
            #pragma unroll
            for (int dx = 0; dx < 4; ++dx) {
                int xx = xx0 + dx;
                float val = 0.f;
                if (yok && (unsigned)xx < 32u) val = src[(ic << 10) + (y << 5) + xx];
                p[dy][dx] = val;
            }
        }
        #pragma unroll
        for (int o = 0; o < 8; ++o) {
            int oc = ocg * 8 + o;
            const float* wp = w + (oc * 16 + ic) * 9;
            #pragma unroll
            for (int ky = 0; ky < 3; ++ky)
                #pragma unroll
                for (int kx = 0; kx < 3; ++kx) {
                    float wv = wp[ky * 3 + kx];
                    acc[o][0] = fmaf(p[ky][kx],     wv, acc[o][0]);
                    acc[o][1] = fmaf(p[ky][kx + 1], wv, acc[o][1]);
                    acc[o][2] = fmaf(p[ky + 1][kx],     wv, acc[o][2]);
                    acc[o][3] = fmaf(p[ky + 1][kx + 1], wv, acc[o][3]);
                }
        }
    }
    #pragma unroll
    for (int o = 0; o < 8; ++o) {
        int oc = ocg * 8 + o;
        float inv = g[oc] * rsqrtf(v[oc] + 1e-5f);
        float bs  = (cb[oc] - m[oc]) * inv + beta[oc];
        float r = fmaxf(fmaxf(fmaxf(acc[o][0] * inv + bs, 0.f), fmaxf(acc[o][1] * inv + bs, 0.f)),
                        fmaxf(fmaxf(acc[o][2] * inv + bs, 0.f), fmaxf(acc[o][3] * inv + bs, 0.f)));
        out[(((size_t)b * 32 + oc) << 8) + (ph << 4) + pw] = r;
    }
}

// ---------------- Layer 3: conv 32->64 (3x3 SAME, 16x16) + bn + relu + maxpool2 -> 64x8x8
__global__ __launch_bounds__(256) void k_conv3(const float* __restrict__ in,
    const float* __restrict__ w, const float* __restrict__ cb,
    const float* __restrict__ g, const float* __restrict__ beta,
    const float* __restrict__ m, const float* __restrict__ v,
    float* __restrict__ out)
{
    int bid = blockIdx.x;               // 1024 blocks
    int b = bid >> 1, half = bid & 1;
    int t = threadIdx.x;
    int pos = t & 63, og = t >> 6;      // 4 oc-groups per block
    int pw = pos & 7, ph = pos >> 3;
    int ocbase = half * 32 + og * 8;
    const float* src = in + (size_t)b * 32 * 256;
    float acc[8][4];
    #pragma unroll
    for (int o = 0; o < 8; ++o)
        #pragma unroll
        for (int j = 0; j < 4; ++j) acc[o][j] = 0.f;
    int y0 = 2 * ph - 1, xx0 = 2 * pw - 1;
    for (int ic = 0; ic < 32; ++ic) {
        float p[4][4];
        #pragma unroll
        for (int dy = 0; dy < 4; ++dy) {
            int y = y0 + dy;
            bool yok = (unsigned)y < 16u;
            #pragma unroll
            for (int dx = 0; dx < 4; ++dx) {
                int xx = xx0 + dx;
                float val = 0.f;
                if (yok && (unsigned)xx < 16u) val = src[(ic << 8) + (y << 4) + xx];
                p[dy][dx] = val;
            }
        }
        #pragma unroll
        for (int o = 0; o < 8; ++o) {
            int oc = ocbase + o;
            const float* wp = w + (oc * 32 + ic) * 9;
            #pragma unroll
            for (int ky = 0; ky < 3; ++ky)
                #pragma unroll
                for (int kx = 0; kx < 3; ++kx) {
                    float wv = wp[ky * 3 + kx];
                    acc[o][0] = fmaf(p[ky][kx],     wv, acc[o][0]);
                    acc[o][1] = fmaf(p[ky][kx + 1], wv, acc[o][1]);
                    acc[o][2] = fmaf(p[ky + 1][kx],     wv, acc[o][2]);
                    acc[o][3] = fmaf(p[ky + 1][kx + 1], wv, acc[o][3]);
                }
        }
    }
    #pragma unroll
    for (int o = 0; o < 8; ++o) {
        int oc = ocbase + o;
        float inv = g[oc] * rsqrtf(v[oc] + 1e-5f);
        float bs  = (cb[oc] - m[oc]) * inv + beta[oc];
        float r = fmaxf(fmaxf(fmaxf(acc[o][0] * inv + bs, 0.f), fmaxf(acc[o][1] * inv + bs, 0.f)),
                        fmaxf(fmaxf(acc[o][2] * inv + bs, 0.f), fmaxf(acc[o][3] * inv + bs, 0.f)));
        out[(((size_t)b * 64 + oc) << 6) + (ph << 3) + pw] = r;
    }
}

// ---------------- Head: projection + tanh + analytic quantum map + classifier
// single[i] = prod_{q<=i} cos(theta_q); pair(i,j) = prod_{q=i+1..j} cos(theta_q)
// one wave per (b, k); atomicAdd into zeroed d_out
__global__ __launch_bounds__(256) void k_head(const float* __restrict__ h3,
    const float* __restrict__ pjw, const float* __restrict__ pjb,
    const float* __restrict__ cw, const float* __restrict__ cbias,
    float* __restrict__ out)
{
    int wid = (blockIdx.x << 2) + (threadIdx.x >> 6);  // 8192 waves
    int lane = threadIdx.x & 63;
    int b = wid >> 4, k = wid & 15;
    const float* f = h3 + (size_t)b * 4096 + k * 256;
    float fv[4];
    #pragma unroll
    for (int j = 0; j < 4; ++j) fv[j] = f[lane + 64 * j];
    const float* wp = pjw + k * 2048;     // [256][8]
    float wv[4][8];
    #pragma unroll
    for (int j = 0; j < 4; ++j) {
        const float4* q4 = (const float4*)(wp + (lane + 64 * j) * 8);
        float4 lo = q4[0], hi = q4[1];
        wv[j][0] = lo.x; wv[j][1] = lo.y; wv[j][2] = lo.z; wv[j][3] = lo.w;
        wv[j][4] = hi.x; wv[j][5] = hi.y; wv[j][6] = hi.z; wv[j][7] = hi.w;
    }
    float cz[8];
    #pragma unroll
    for (int d = 0; d < 8; ++d) {
        float s = fv[0] * wv[0][d] + fv[1] * wv[1][d] + fv[2] * wv[2][d] + fv[3] * wv[3][d];
        #pragma unroll
        for (int off = 32; off; off >>= 1) s += __shfl_xor(s, off, 64);
        float z = s + pjb[k * 8 + d];
        cz[d] = cosf(0.5f * tanhf(z));
    }
    float qf[36];
    float pp = 1.f;
    #pragma unroll
    for (int i = 0; i < 8; ++i) { pp *= cz[i]; qf[i] = pp; }
    int cnt = 8;
    #pragma unroll
    for (int i = 0; i < 8; ++i) {
        float p2 = 1.f;
        #pragma unroll
        for (int j = i + 1; j < 8; ++j) { p2 *= cz[j]; qf[cnt++] = p2; }
    }
    if (lane < 10) {
        const float* cwp = cw + lane * 576 + k * 36;
        float s = 0.f;
        #pragma unroll
        for (int f2 = 0; f2 < 36; ++f2) s = fmaf(qf[f2], cwp[f2], s);
        if (k == 0) s += cbias[lane];
        atomicAdd(out + b * 10 + lane, s);
    }
}

extern "C" void kernel_launch(void* const* d_in, const int* in_sizes, int n_in,
                              void* d_out, int out_size, void* d_ws, size_t ws_size,
                              hipStream_t stream) {
    const float* x       = (const float*)d_in[0];
    const float* c1w     = (const float*)d_in[1];
    const float* c1b     = (const float*)d_in[2];
    const float* b1g     = (const float*)d_in[3];
    const float* b1b     = (const float*)d_in[4];
    const float* b1m     = (const float*)d_in[5];
    const float* b1v     = (const float*)d_in[6];
    const float* c2w     = (const float*)d_in[7];
    const float* c2b     = (const float*)d_in[8];
    const float* b2g     = (const float*)d_in[9];
    const float* b2b     = (const float*)d_in[10];
    const float* b2m     = (const float*)d_in[11];
    const float* b2v     = (const float*)d_in[12];
    const float* c3w     = (const float*)d_in[13];
    const float* c3b     = (const float*)d_in[14];
    const float* b3g     = (const float*)d_in[15];
    const float* b3b     = (const float*)d_in[16];
    const float* b3m     = (const float*)d_in[17];
    const float* b3v     = (const float*)d_in[18];
    const float* pjw     = (const float*)d_in[19];
    const float* pjb     = (const float*)d_in[20];
    const float* cw      = (const float*)d_in[21];
    const float* cbias   = (const float*)d_in[22];
    float* outp = (float*)d_out;

    // workspace: region A (8,388,608 floats) ping-pongs h1 then h3; region B holds h2
    float* A  = (float*)d_ws;
    float* Bp = A + 8388608;

    // h1 = A: 512x16x32x32
    k_conv1<<<2048, 256, 0, stream>>>(x, c1w, c1b, b1g, b1b, b1m, b1v, A);
    // h2 = B: 512x32x16x16
    k_conv2<<<2048, 256, 0, stream>>>(A, c2w, c2b, b2g, b2b, b2m, b2v, Bp);
    // h3 = A: 512x64x8x8 (h1 dead)
    k_conv3<<<1024, 256, 0, stream>>>(Bp, c3w, c3b, b3g, b3b, b3m, b3v, A);
    // logits
    hipMemsetAsync(d_out, 0, (size_t)out_size * sizeof(float), stream);
    k_head<<<2048, 256, 0, stream>>>(A, pjw, pjb, cw, cbias, outp);
}

// Round 2
// 295.530 us; speedup vs baseline: 1.2658x; 1.2658x over previous
//
#include <hip/hip_runtime.h>
#include <hip/hip_bf16.h>
#include <math.h>

#define BATCH 512

// ---------------- Layer 1: conv 3->16 (3x3 SAME, 64x64) + bn + relu + maxpool2 -> 16x32x32
// grid 1024: (b, half). LDS-padded half-image tile [3][34][66].
__global__ __launch_bounds__(256) void k_conv1(const float* __restrict__ x,
    const float* __restrict__ w, const float* __restrict__ cb,
    const float* __restrict__ g, const float* __restrict__ beta,
    const float* __restrict__ m, const float* __restrict__ v,
    float* __restrict__ out)
{
    __shared__ float tile[3 * 34 * 66];   // 6732 floats = 26.3 KB
    int bid = blockIdx.x;
    int b = bid >> 1, half = bid & 1;
    const float* img = x + (size_t)b * 3 * 4096;
    int y0 = 32 * half - 1;
    for (int idx = threadIdx.x; idx < 6732; idx += 256) {
        int ic = idx / 2244, rem = idx % 2244;
        int yy = rem / 66, xxp = rem % 66;
        int y = y0 + yy, xx = xxp - 1;
        float val = 0.f;
        if ((unsigned)y < 64u && (unsigned)xx < 64u) val = img[ic * 4096 + y * 64 + xx];
        tile[idx] = val;
    }
    __syncthreads();
    #pragma unroll 1
    for (int it = 0; it < 2; ++it) {
        int pos = threadIdx.x + it * 256;          // 512 pooled positions per block
        int pw = pos & 31, phl = pos >> 5;         // phl 0..15
        float p[3][4][4];
        #pragma unroll
        for (int ic = 0; ic < 3; ++ic)
            #pragma unroll
            for (int dy = 0; dy < 4; ++dy)
                #pragma unroll
                for (int dx = 0; dx < 4; ++dx)
                    p[ic][dy][dx] = tile[ic * 2244 + (2 * phl + dy) * 66 + 2 * pw + dx];
        float* op = out + (size_t)b * 16384 + (half * 16 + phl) * 32 + pw;
        #pragma unroll
        for (int oc = 0; oc < 16; ++oc) {
            float inv = g[oc] * rsqrtf(v[oc] + 1e-5f);
            float bs  = (cb[oc] - m[oc]) * inv + beta[oc];
            float a0 = 0.f, a1 = 0.f, a2 = 0.f, a3 = 0.f;
            #pragma unroll
            for (int ic = 0; ic < 3; ++ic)
                #pragma unroll
                for (int ky = 0; ky < 3; ++ky)
                    #pragma unroll
                    for (int kx = 0; kx < 3; ++kx) {
                        float wv = w[((oc * 3 + ic) * 3 + ky) * 3 + kx];
                        a0 = fmaf(p[ic][ky][kx],         wv, a0);
                        a1 = fmaf(p[ic][ky][kx + 1],     wv, a1);
                        a2 = fmaf(p[ic][ky + 1][kx],     wv, a2);
                        a3 = fmaf(p[ic][ky + 1][kx + 1], wv, a3);
                    }
            float r = fmaxf(fmaxf(fmaxf(a0 * inv + bs, 0.f), fmaxf(a1 * inv + bs, 0.f)),
                            fmaxf(fmaxf(a2 * inv + bs, 0.f), fmaxf(a3 * inv + bs, 0.f)));
            op[oc * 1024] = r;
        }
    }
}

// ---------------- Layer 2: conv 16->32 (3x3 SAME, 32x32) + bn + relu + maxpool2 -> 32x16x16
// grid 1024: (b, ocg of 16 oc). LDS-padded tile [8 ic][34][34], 2 ic-chunks.
__global__ __launch_bounds__(256) void k_conv2(const float* __restrict__ in,
    const float* __restrict__ w, const float* __restrict__ cb,
    const float* __restrict__ g, const float* __restrict__ beta,
    const float* __restrict__ m, const float* __restrict__ v,
    float* __restrict__ out)
{
    __shared__ float tile[8 * 34 * 34];   // 9248 floats = 37 KB
    int bid = blockIdx.x;
    int b = bid >> 1, ocg = bid & 1;
    const float* src = in + (size_t)b * 16384;
    int t = threadIdx.x;
    int pw = t & 15, ph = t >> 4;
    float acc[16][4];
    #pragma unroll
    for (int o = 0; o < 16; ++o)
        #pragma unroll
        for (int j = 0; j < 4; ++j) acc[o][j] = 0.f;
    #pragma unroll 1
    for (int c = 0; c < 2; ++c) {
        if (c) __syncthreads();
        for (int idx = t; idx < 9248; idx += 256) {
            int icc = idx / 1156, rem = idx % 1156;
            int yy = rem / 34, xxp = rem % 34;
            int y = yy - 1, xx = xxp - 1;
            float val = 0.f;
            if ((unsigned)y < 32u && (unsigned)xx < 32u) val = src[(c * 8 + icc) * 1024 + y * 32 + xx];
            tile[idx] = val;
        }
        __syncthreads();
        #pragma unroll 1
        for (int icc = 0; icc < 8; ++icc) {
            float p[4][4];
            #pragma unroll
            for (int dy = 0; dy < 4; ++dy)
                #pragma unroll
                for (int dx = 0; dx < 4; ++dx)
                    p[dy][dx] = tile[icc * 1156 + (2 * ph + dy) * 34 + 2 * pw + dx];
            int ic = c * 8 + icc;
            #pragma unroll
            for (int o = 0; o < 16; ++o) {
                int oc = ocg * 16 + o;
                const float* wp = w + (oc * 16 + ic) * 9;
                #pragma unroll
                for (int ky = 0; ky < 3; ++ky)
                    #pragma unroll
                    for (int kx = 0; kx < 3; ++kx) {
                        float wv = wp[ky * 3 + kx];
                        acc[o][0] = fmaf(p[ky][kx],         wv, acc[o][0]);
                        acc[o][1] = fmaf(p[ky][kx + 1],     wv, acc[o][1]);
                        acc[o][2] = fmaf(p[ky + 1][kx],     wv, acc[o][2]);
                        acc[o][3] = fmaf(p[ky + 1][kx + 1], wv, acc[o][3]);
                    }
            }
        }
    }
    #pragma unroll
    for (int o = 0; o < 16; ++o) {
        int oc = ocg * 16 + o;
        float inv = g[oc] * rsqrtf(v[oc] + 1e-5f);
        float bs  = (cb[oc] - m[oc]) * inv + beta[oc];
        float r = fmaxf(fmaxf(fmaxf(acc[o][0] * inv + bs, 0.f), fmaxf(acc[o][1] * inv + bs, 0.f)),
                        fmaxf(fmaxf(acc[o][2] * inv + bs, 0.f), fmaxf(acc[o][3] * inv + bs, 0.f)));
        out[(((size_t)b * 32 + oc) << 8) + (ph << 4) + pw] = r;
    }
}

// ---------------- Layer 3: conv 32->64 (3x3 SAME, 16x16) + bn + relu + maxpool2 -> 64x8x8
// grid 1024: (b, half of 32 oc). 256 threads = 64 pos x 4 og (8 oc each).
// LDS-padded tile [16 ic][18][18], 2 ic-chunks.
__global__ __launch_bounds__(256) void k_conv3(const float* __restrict__ in,
    const float* __restrict__ w, const float* __restrict__ cb,
    const float* __restrict__ g, const float* __restrict__ beta,
    const float* __restrict__ m, const float* __restrict__ v,
    float* __restrict__ out)
{
    __shared__ float tile[16 * 18 * 18];  // 5184 floats = 20.25 KB
    int bid = blockIdx.x;
    int b = bid >> 1, half = bid & 1;
    int t = threadIdx.x;
    int og = __builtin_amdgcn_readfirstlane(t >> 6);   // wave-uniform -> scalar weight loads
    int pos = t & 63, pw = pos & 7, ph = pos >> 3;
    int ocbase = half * 32 + og * 8;
    const float* src = in + (size_t)b * 8192;
    float acc[8][4];
    #pragma unroll
    for (int o = 0; o < 8; ++o)
        #pragma unroll
        for (int j = 0; j < 4; ++j) acc[o][j] = 0.f;
    #pragma unroll 1
    for (int c = 0; c < 2; ++c) {
        if (c) __syncthreads();
        for (int idx = t; idx < 5184; idx += 256) {
            int icc = idx / 324, rem = idx % 324;
            int yy = rem / 18, xxp = rem % 18;
            int y = yy - 1, xx = xxp - 1;
            float val = 0.f;
            if ((unsigned)y < 16u && (unsigned)xx < 16u) val = src[(c * 16 + icc) * 256 + y * 16 + xx];
            tile[idx] = val;
        }
        __syncthreads();
        #pragma unroll 1
        for (int icc = 0; icc < 16; ++icc) {
            float p[4][4];
            #pragma unroll
            for (int dy = 0; dy < 4; ++dy)
                #pragma unroll
                for (int dx = 0; dx < 4; ++dx)
                    p[dy][dx] = tile[icc * 324 + (2 * ph + dy) * 18 + 2 * pw + dx];
            int ic = c * 16 + icc;
            #pragma unroll
            for (int o = 0; o < 8; ++o) {
                int oc = ocbase + o;
                const float* wp = w + (oc * 32 + ic) * 9;
                #pragma unroll
                for (int ky = 0; ky < 3; ++ky)
                    #pragma unroll
                    for (int kx = 0; kx < 3; ++kx) {
                        float wv = wp[ky * 3 + kx];
                        acc[o][0] = fmaf(p[ky][kx],         wv, acc[o][0]);
                        acc[o][1] = fmaf(p[ky][kx + 1],     wv, acc[o][1]);
                        acc[o][2] = fmaf(p[ky + 1][kx],     wv, acc[o][2]);
                        acc[o][3] = fmaf(p[ky + 1][kx + 1], wv, acc[o][3]);
                    }
            }
        }
    }
    #pragma unroll
    for (int o = 0; o < 8; ++o) {
        int oc = ocbase + o;
        float inv = g[oc] * rsqrtf(v[oc] + 1e-5f);
        float bs  = (cb[oc] - m[oc]) * inv + beta[oc];
        float r = fmaxf(fmaxf(fmaxf(acc[o][0] * inv + bs, 0.f), fmaxf(acc[o][1] * inv + bs, 0.f)),
                        fmaxf(fmaxf(acc[o][2] * inv + bs, 0.f), fmaxf(acc[o][3] * inv + bs, 0.f)));
        out[(((size_t)b * 64 + oc) << 6) + (ph << 3) + pw] = r;
    }
}

// ---------------- Head: projection + tanh + analytic quantum map + classifier
// single[i] = prod_{q<=i} cos(theta_q); pair(i,j) = prod_{q=i+1..j} cos(theta_q)
__global__ __launch_bounds__(256) void k_head(const float* __restrict__ h3,
    const float* __restrict__ pjw, const float* __restrict__ pjb,
    const float* __restrict__ cw, const float* __restrict__ cbias,
    float* __restrict__ out)
{
    int wid = (blockIdx.x << 2) + (threadIdx.x >> 6);  // 8192 waves
    int lane = threadIdx.x & 63;
    int b = wid >> 4, k = wid & 15;
    const float* f = h3 + (size_t)b * 4096 + k * 256;
    float fv[4];
    #pragma unroll
    for (int j = 0; j < 4; ++j) fv[j] = f[lane + 64 * j];
    const float* wp = pjw + k * 2048;     // [256][8]
    float wv[4][8];
    #pragma unroll
    for (int j = 0; j < 4; ++j) {
        const float4* q4 = (const float4*)(wp + (lane + 64 * j) * 8);
        float4 lo = q4[0], hi = q4[1];
        wv[j][0] = lo.x; wv[j][1] = lo.y; wv[j][2] = lo.z; wv[j][3] = lo.w;
        wv[j][4] = hi.x; wv[j][5] = hi.y; wv[j][6] = hi.z; wv[j][7] = hi.w;
    }
    float cz[8];
    #pragma unroll
    for (int d = 0; d < 8; ++d) {
        float s = fv[0] * wv[0][d] + fv[1] * wv[1][d] + fv[2] * wv[2][d] + fv[3] * wv[3][d];
        #pragma unroll
        for (int off = 32; off; off >>= 1) s += __shfl_xor(s, off, 64);
        float z = s + pjb[k * 8 + d];
        cz[d] = cosf(0.5f * tanhf(z));
    }
    float qf[36];
    float pp = 1.f;
    #pragma unroll
    for (int i = 0; i < 8; ++i) { pp *= cz[i]; qf[i] = pp; }
    int cnt = 8;
    #pragma unroll
    for (int i = 0; i < 8; ++i) {
        float p2 = 1.f;
        #pragma unroll
        for (int j = i + 1; j < 8; ++j) { p2 *= cz[j]; qf[cnt++] = p2; }
    }
    if (lane < 10) {
        const float* cwp = cw + lane * 576 + k * 36;
        float s = 0.f;
        #pragma unroll
        for (int f2 = 0; f2 < 36; ++f2) s = fmaf(qf[f2], cwp[f2], s);
        if (k == 0) s += cbias[lane];
        atomicAdd(out + b * 10 + lane, s);
    }
}

extern "C" void kernel_launch(void* const* d_in, const int* in_sizes, int n_in,
                              void* d_out, int out_size, void* d_ws, size_t ws_size,
                              hipStream_t stream) {
    const float* x       = (const float*)d_in[0];
    const float* c1w     = (const float*)d_in[1];
    const float* c1b     = (const float*)d_in[2];
    const float* b1g     = (const float*)d_in[3];
    const float* b1b     = (const float*)d_in[4];
    const float* b1m     = (const float*)d_in[5];
    const float* b1v     = (const float*)d_in[6];
    const float* c2w     = (const float*)d_in[7];
    const float* c2b     = (const float*)d_in[8];
    const float* b2g     = (const float*)d_in[9];
    const float* b2b     = (const float*)d_in[10];
    const float* b2m     = (const float*)d_in[11];
    const float* b2v     = (const float*)d_in[12];
    const float* c3w     = (const float*)d_in[13];
    const float* c3b     = (const float*)d_in[14];
    const float* b3g     = (const float*)d_in[15];
    const float* b3b     = (const float*)d_in[16];
    const float* b3m     = (const float*)d_in[17];
    const float* b3v     = (const float*)d_in[18];
    const float* pjw     = (const float*)d_in[19];
    const float* pjb     = (const float*)d_in[20];
    const float* cw      = (const float*)d_in[21];
    const float* cbias   = (const float*)d_in[22];
    float* outp = (float*)d_out;

    float* A  = (float*)d_ws;          // h1: 512x16x32x32 then h3: 512x64x8x8
    float* Bp = A + 8388608;           // h2: 512x32x16x16

    k_conv1<<<1024, 256, 0, stream>>>(x, c1w, c1b, b1g, b1b, b1m, b1v, A);
    k_conv2<<<1024, 256, 0, stream>>>(A, c2w, c2b, b2g, b2b, b2m, b2v, Bp);
    k_conv3<<<1024, 256, 0, stream>>>(Bp, c3w, c3b, b3g, b3b, b3m, b3v, A);
    hipMemsetAsync(d_out, 0, (size_t)out_size * sizeof(float), stream);
    k_head<<<2048, 256, 0, stream>>>(A, pjw, pjb, cw, cbias, outp);
}